// Round 12
// baseline (673.037 us; speedup 1.0000x reference)
//
#include <hip/hip_runtime.h>
#include <hip/hip_bf16.h>
#include <math.h>

// N=200000 nodes, U=100000 users, D=64, L=3, E=3,000,000 per edge list, NLINK=100000.
// Node buffers FP16; aggregation accumulates via v_dot2_f32_f16.
// Agg: r5 floor config (TRIPLE-confirmed delivery-ceiling: VALU cut r5, MLP up
// r7/r10, junk-request cut r8 all null) — 16 lanes/node, 4 nodes/wave, 8-slot
// blocks, 4 row-loads in flight, clamp+subtract fixup. DO NOT TOUCH.
// Prep: STATIC bucket bases; bin3 + W/emb-conv + pred0 merged into ONE dispatch
// (mutually independent; stream-serial before). CSR is (rs, deg) pairs.
// L3: BOTH lists flag-skipped (only link-endpoint rows are read downstream);
// mix3 waves with no flagged users skip entirely.
// Wide mode: node buffers as contiguous PAIRS (A|B, C|Dd); t-chain gathers use
// remapped col_t (src<U ? src : src+N) sharing user rows with the s-chain.

typedef unsigned short u16;
typedef unsigned int   u32;
typedef __attribute__((ext_vector_type(2))) _Float16 h16x2;
typedef __attribute__((ext_vector_type(8))) _Float16 f16x8;
typedef __attribute__((ext_vector_type(4))) float f32x4;

#define BSHIFT 8                 // 256 nodes per coarse bucket
#define NODESB 256               // nodes per bucket
#define NBPAD  1024              // padded bucket-cursor array (782 used)
#define BCKCAP 4352              // static bucket capacity (mean 3840, +8 sigma)
#define BCAP   4096              // LDS staging per sort bucket
#define OVF    8                 // +2048 entries of per-thread register headroom
#define BCHUNK 8192              // edges per bin block (LDS presort)

__device__ __forceinline__ u16 f2h(float f) {
    _Float16 h = (_Float16)f;
    return __builtin_bit_cast(u16, h);
}
__device__ __forceinline__ float h2f(u16 v) {
    _Float16 h = __builtin_bit_cast(_Float16, v);
    return (float)h;
}
__device__ __forceinline__ u32 packh2(float a, float b) {
    auto r = __builtin_amdgcn_cvt_pkrtz(a, b);   // v_cvt_pkrtz_f16_f32 (__fp16 x2)
    return __builtin_bit_cast(u32, r);
}
__device__ __forceinline__ float hlo(u32 p) {
    h16x2 h = __builtin_bit_cast(h16x2, p);
    return (float)h.x;
}
__device__ __forceinline__ float hhi(u32 p) {
    h16x2 h = __builtin_bit_cast(h16x2, p);
    return (float)h.y;
}
__device__ __forceinline__ int imin(int a, int b) { return a < b ? a : b; }

#if defined(__has_builtin)
#if __has_builtin(__builtin_amdgcn_fdot2)
#define HAVE_FDOT2 1
#endif
#endif

// ---- D1: MERGED bin3 (LDS presort, static bases) + W/emb->f16 conv + pred0 ----
// Block roles by blockIdx: [0, 2*nbin) bin ; [.., +nwprep+nconv) conv ; rest pred0.
// Bin blocks come first so sort2's dependency drains earliest; conv/pred0 overlap.
__global__ __launch_bounds__(256) void prep_all(
        const int* __restrict__ ssrc, const int* __restrict__ sdst,
        const int* __restrict__ tsrc, const int* __restrict__ tdst, int e,
        int* __restrict__ cur2, u32* __restrict__ bin_s, u32* __restrict__ bin_t, int nbin,
        const float* __restrict__ mw, u16* __restrict__ mwb,
        const float* __restrict__ emb, u32* __restrict__ embb, int nelem, int nwprep, int nconv,
        const int* __restrict__ l0, const int* __restrict__ l1,
        const float* __restrict__ pw, float* __restrict__ acc, int nl,
        unsigned char* __restrict__ flag) {
    __shared__ u32 stage[BCHUNK];       // 32KB bucket-sorted staging (bin branch only)
    __shared__ int lcnt[NBPAD];
    __shared__ int lofs[NBPAD];
    __shared__ int lbase[NBPAD];
    __shared__ int part[256];
    int bid = blockIdx.x, tid = threadIdx.x;
    if (bid < 2 * nbin) {
        const int* src; const int* dst; int* cursor; u32* bin; int cb;
        if (bid < nbin) { src = ssrc; dst = sdst; cursor = cur2; bin = bin_s; cb = bid; }
        else { src = tsrc; dst = tdst; cursor = cur2 + NBPAD; bin = bin_t; cb = bid - nbin; }
        for (int i = tid; i < NBPAD; i += 256) lcnt[i] = 0;
        __syncthreads();
        int base = cb * BCHUNK, end = imin(base + BCHUNK, e);
        // A: histogram chunk by bucket
        for (int i = base + tid; i < end; i += 256)
            atomicAdd(&lcnt[(u32)dst[i] >> BSHIFT], 1);
        __syncthreads();
        // B: block scan -> lofs; bulk reservation (static base + cursor) -> lbase
        {
            int i0 = tid * 4;
            int c[4]; int s = 0;
#pragma unroll
            for (int j = 0; j < 4; ++j) { c[j] = lcnt[i0 + j]; s += c[j]; }
            part[tid] = s;
            __syncthreads();
            for (int off = 1; off < 256; off <<= 1) {
                int t = (tid >= off) ? part[tid - off] : 0;
                __syncthreads();
                part[tid] += t;
                __syncthreads();
            }
            int excl = part[tid] - s;
#pragma unroll
            for (int j = 0; j < 4; ++j) {
                int idx = i0 + j;
                lofs[idx]  = excl;
                lbase[idx] = c[j] ? (idx * BCKCAP + atomicAdd(&cursor[idx], c[j])) : 0;
                lcnt[idx]  = excl;          // scatter cursor starts at bucket start
                excl += c[j];
            }
        }
        __syncthreads();
        // C: scatter entries into LDS staging, bucket-sorted
        for (int i = base + tid; i < end; i += 256) {
            int d = dst[i];
            int b = (u32)d >> BSHIFT;
            int p = atomicAdd(&lcnt[b], 1);
            stage[p] = (u32)src[i] | ((u32)(d & (NODESB - 1)) << 18);   // src < 2^18
        }
        __syncthreads();
        // D: flush segments, 4 lanes per bucket -> contiguous burst writes
        for (int bb = tid >> 2; bb < NBPAD; bb += 64) {
            int lo = lofs[bb];
            int cnt = lcnt[bb] - lo;
            int gb = lbase[bb];
            for (int j = tid & 3; j < cnt; j += 4)
                bin[gb + j] = stage[lo + j];
        }
        return;
    }
    bid -= 2 * nbin;
    if (bid < nwprep + nconv) {
        if (bid < nwprep) {
            int idx = bid * 256 + tid;
            if (idx < 3 * 64 * 128) mwb[idx] = f2h(mw[idx]);
        } else {
            int idx = (bid - nwprep) * 1024 + tid * 4;   // 4 floats / thread
            if (idx < nelem) {
                float4 v = *(const float4*)(emb + idx);
                uint2 r;
                r.x = packh2(v.x, v.y);
                r.y = packh2(v.z, v.w);
                *(uint2*)(embb + (idx >> 1)) = r;
            }
        }
        return;
    }
    bid -= nwprep + nconv;
    int li = bid * 4 + (tid >> 6);
    if (li >= nl) return;
    li = __builtin_amdgcn_readfirstlane(li);
    int lane = tid & 63;
    int u = l0[li], v = l1[li];
    if (lane == 0) { flag[u] = 1; flag[v] = 1; }   // L3 liveness
    float s = pw[lane] * emb[(size_t)u * 64 + lane] + pw[256 + lane] * emb[(size_t)v * 64 + lane];
#pragma unroll
    for (int off = 32; off > 0; off >>= 1) s += __shfl_xor(s, off, 64);
    if (lane == 0) acc[li] = s;
}

// ---- D4: fused per-bucket counting sort (both lists), in place; static bases ----
// Emits CSR as (rowstart, degree) pairs — rowstart is NOT cumulative across
// buckets (static bases), so degree must be explicit.
__global__ __launch_bounds__(256) void sort2_kernel(u32* __restrict__ bin_s, u32* __restrict__ bin_t,
        const int* __restrict__ cnt_s, const int* __restrict__ cnt_t,
        int* __restrict__ rs_s, int* __restrict__ rs_t,
        int* __restrict__ dg_s, int* __restrict__ dg_t, int n, int nb) {
    __shared__ u32 ent[BCAP];
    __shared__ int cnt[NODESB];
    __shared__ int part[256];
    int bid = blockIdx.x, tid = threadIdx.x;
    u32* bin; const int* bcnt; int* rowstart; int* degarr; int b;
    if (bid < nb) { bin = bin_s; bcnt = cnt_s; rowstart = rs_s; degarr = dg_s; b = bid; }
    else { bin = bin_t; bcnt = cnt_t; rowstart = rs_t; degarr = dg_t; b = bid - nb; }
    int beg = b * BCKCAP;
    int sz = bcnt[b];
    cnt[tid] = 0;
    __syncthreads();
    u32 ovf[OVF];
    for (int i = tid; i < sz; i += 256) {
        u32 v = bin[beg + i];
        if (i < BCAP) ent[i] = v;
        else { int k = (i - BCAP) >> 8; if (k < OVF) ovf[k] = v; }
        atomicAdd(&cnt[v >> 18], 1);
    }
    __syncthreads();
    int c = cnt[tid];
    part[tid] = c;
    __syncthreads();
    for (int off = 1; off < 256; off <<= 1) {
        int t = (tid >= off) ? part[tid - off] : 0;
        __syncthreads();
        part[tid] += t;
        __syncthreads();
    }
    int excl = part[tid] - c;
    int node = (b << BSHIFT) + tid;
    if (node < n) { rowstart[node] = beg + excl; degarr[node] = c; }
    cnt[tid] = excl;             // running cursor for scatter phase
    __syncthreads();
    for (int i = tid; i < sz; i += 256) {
        u32 v;
        if (i < BCAP) v = ent[i];
        else { int k = (i - BCAP) >> 8; v = (k < OVF) ? ovf[k] : bin[beg + i]; }
        int pos = atomicAdd(&cnt[v >> 18], 1);
        bin[beg + pos] = v & 0x3FFFFu;
    }
}

// ---- mean aggregation (f16 in/out, fdot2) + fused predictor blocks ----
// r5 floor config: 16 lanes/node (8 feat x 2 groups), 4 nodes/wave, 8-slot
// blocks with FOUR row loads in flight; clamped slots overcount row[col[dgm1]]
// (last block only), removed by exact conditional subtracts after the loop.
__global__ __launch_bounds__(256) void aggp_kernel(
        const u32* __restrict__ x0, const int* __restrict__ rsA, const int* __restrict__ dgA,
        const u32* __restrict__ colA, u32* __restrict__ outA, int nblkA, int nA,
        const unsigned char* __restrict__ skipA,
        const u32* __restrict__ x1, const int* __restrict__ rsB, const int* __restrict__ dgB,
        const u32* __restrict__ colB, u32* __restrict__ outB, int nblkB, int nB,
        const unsigned char* __restrict__ skipB,
        const u16* __restrict__ px, const int* __restrict__ l0, const int* __restrict__ l1,
        const float* __restrict__ pw, int ofA, int ofB, float* __restrict__ acc, int nl,
        int npred) {
    int bid = blockIdx.x;
    int lane = threadIdx.x & 63;
    if (bid < npred) {
        int li = bid * 4 + (threadIdx.x >> 6);
        if (li >= nl) return;
        li = __builtin_amdgcn_readfirstlane(li);
        int u = l0[li], v = l1[li];
        float s = pw[ofA + lane] * h2f(px[(size_t)u * 64 + lane])
                + pw[ofB + lane] * h2f(px[(size_t)v * 64 + lane]);
#pragma unroll
        for (int off = 32; off > 0; off >>= 1) s += __shfl_xor(s, off, 64);
        if (lane == 0) acc[li] += s;
        return;
    }
    bid -= npred;
    const u32* xin; const int* rs; const int* dg; const u32* col; u32* out; int nlim;
    const unsigned char* skip;
    if (bid < nblkA) { xin = x0; rs = rsA; dg = dgA; col = colA; out = outA; nlim = nA; skip = skipA; }
    else { bid -= nblkA; xin = x1; rs = rsB; dg = dgB; col = colB; out = outB; nlim = nB; skip = skipB; }
    int node = bid * 16 + (threadIdx.x >> 4);   // one node per 16-lane quarter-wave
    if (node >= nlim) return;
    if (skip && !skip[node]) return;            // output never read downstream
    int fl = lane & 7;            // feature octet: features 8fl .. 8fl+7
    int g  = (lane >> 3) & 1;     // edge group 0..1 within the 16-lane group
    int beg = rs[node];
    int dgv = dg[node];
    int dgm1 = dgv - 1;
    float a0 = 0.f, a1 = 0.f, a2 = 0.f, a3 = 0.f, a4 = 0.f, a5 = 0.f, a6 = 0.f, a7 = 0.f;
    uint4 p0 = make_uint4(0, 0, 0, 0), p1 = make_uint4(0, 0, 0, 0);
    uint4 p2 = make_uint4(0, 0, 0, 0), p3 = make_uint4(0, 0, 0, 0);
    const uint4* xb = (const uint4*)xin;
    const h16x2 SLO = {(_Float16)1.f, (_Float16)0.f};
    const h16x2 SHI = {(_Float16)0.f, (_Float16)1.f};
#ifdef HAVE_FDOT2
#define ACC8(P) { \
    h16x2 w0 = __builtin_bit_cast(h16x2, (P).x), w1 = __builtin_bit_cast(h16x2, (P).y); \
    h16x2 w2 = __builtin_bit_cast(h16x2, (P).z), w3 = __builtin_bit_cast(h16x2, (P).w); \
    a0 = __builtin_amdgcn_fdot2(w0, SLO, a0, false); a1 = __builtin_amdgcn_fdot2(w0, SHI, a1, false); \
    a2 = __builtin_amdgcn_fdot2(w1, SLO, a2, false); a3 = __builtin_amdgcn_fdot2(w1, SHI, a3, false); \
    a4 = __builtin_amdgcn_fdot2(w2, SLO, a4, false); a5 = __builtin_amdgcn_fdot2(w2, SHI, a5, false); \
    a6 = __builtin_amdgcn_fdot2(w3, SLO, a6, false); a7 = __builtin_amdgcn_fdot2(w3, SHI, a7, false); }
#else
#define ACC8(P) { \
    a0 += hlo((P).x); a1 += hhi((P).x); a2 += hlo((P).y); a3 += hhi((P).y); \
    a4 += hlo((P).z); a5 += hhi((P).z); a6 += hlo((P).w); a7 += hhi((P).w); }
#endif
#define SUB8(P) { \
    a0 -= hlo((P).x); a1 -= hhi((P).x); a2 -= hlo((P).y); a3 -= hhi((P).y); \
    a4 -= hlo((P).z); a5 -= hhi((P).z); a6 -= hlo((P).w); a7 -= hhi((P).w); }
    if (dgv > 0) {
        int s0 = col[beg + imin(g, dgm1)];
        int s1 = col[beg + imin(g + 2, dgm1)];
        int s2 = col[beg + imin(g + 4, dgm1)];
        int s3 = col[beg + imin(g + 6, dgm1)];
        for (int jb = 0; jb < dgv; jb += 8) {
            p0 = xb[(size_t)s0 * 8 + fl];
            p1 = xb[(size_t)s1 * 8 + fl];
            p2 = xb[(size_t)s2 * 8 + fl];
            p3 = xb[(size_t)s3 * 8 + fl];
            int nj = jb + 8 + g;
            s0 = col[beg + imin(nj, dgm1)];       // prefetch next block's cols
            s1 = col[beg + imin(nj + 2, dgm1)];
            s2 = col[beg + imin(nj + 4, dgm1)];
            s3 = col[beg + imin(nj + 6, dgm1)];
            ACC8(p0); ACC8(p1); ACC8(p2); ACC8(p3);
        }
        int jbl = (dgm1 >> 3) << 3;               // last iteration's block base
        if (jbl + g > dgm1)     SUB8(p0);
        if (jbl + 2 + g > dgm1) SUB8(p1);
        if (jbl + 4 + g > dgm1) SUB8(p2);
        if (jbl + 6 + g > dgm1) SUB8(p3);
    }
    // reduce over the 2 edge groups (lanes x ^ x+8 within each 16-lane node)
    a0 += __shfl_xor(a0, 8, 64); a1 += __shfl_xor(a1, 8, 64);
    a2 += __shfl_xor(a2, 8, 64); a3 += __shfl_xor(a3, 8, 64);
    a4 += __shfl_xor(a4, 8, 64); a5 += __shfl_xor(a5, 8, 64);
    a6 += __shfl_xor(a6, 8, 64); a7 += __shfl_xor(a7, 8, 64);
    if (g == 0) {
        float inv = __builtin_amdgcn_rcpf((float)(dgv > 1 ? dgv : 1));
        uint4 r;
        r.x = packh2(a0 * inv, a1 * inv);
        r.y = packh2(a2 * inv, a3 * inv);
        r.z = packh2(a4 * inv, a5 * inv);
        r.w = packh2(a6 * inv, a7 * inv);
        ((uint4*)out)[(size_t)node * 8 + fl] = r;
    }
#undef ACC8
#undef SUB8
}

// ---- user mix via MFMA (f16) + optional fused col_t remap blocks ----
// uflag != nullptr (mix3): waves whose 16 users are all unflagged skip (their
// output rows are never read by the final predictor).
__global__ __launch_bounds__(256) void mix_mfma(u16* __restrict__ sbuf, u16* __restrict__ tbuf,
        const u16* __restrict__ wb /*[64][128] f16*/, const float* __restrict__ bias, int nu,
        int wt, u32* __restrict__ colt, int ecnt, int nrb, u32 uu, u32 nn,
        const unsigned char* __restrict__ uflag) {
    int bid = blockIdx.x;
    if (bid < nrb) {
        int idx = (bid * 256 + (int)threadIdx.x) * 4;
        if (idx + 3 < ecnt) {
            uint4 v = *(uint4*)(colt + idx);
            v.x = v.x >= uu ? v.x + nn : v.x;
            v.y = v.y >= uu ? v.y + nn : v.y;
            v.z = v.z >= uu ? v.z + nn : v.z;
            v.w = v.w >= uu ? v.w + nn : v.w;
            *(uint4*)(colt + idx) = v;
        } else {
            for (int k = idx; k < ecnt; ++k) { u32 e = colt[k]; colt[k] = e >= uu ? e + nn : e; }
        }
        return;
    }
    bid -= nrb;
    int lane = threadIdx.x & 63;
    int wv = threadIdx.x >> 6;
    int m = lane & 15, q = lane >> 4;
    int ubase = bid * 64 + wv * 16;
    int ul = ubase + m;
    int usafe = ul < nu ? ul : nu - 1;
    if (uflag) {
        unsigned long long any = __ballot(uflag[usafe] != 0);
        if (any == 0ull) return;            // whole wave's 16 users dead
    }
    const f16x8* srow = (const f16x8*)(sbuf + (size_t)usafe * 64);
    const f16x8* trow = (const f16x8*)(tbuf + (size_t)usafe * 64);
    f16x8 a0 = srow[q];
    f16x8 a1 = srow[4 + q];
    f16x8 a2 = trow[q];
    f16x8 a3 = trow[4 + q];
    f32x4 accv[4];
#pragma unroll
    for (int t = 0; t < 4; ++t) { accv[t].x = accv[t].y = accv[t].z = accv[t].w = 0.f; }
#pragma unroll
    for (int t = 0; t < 4; ++t) {
        const u16* wd = wb + (size_t)(t * 16 + m) * 128;
        accv[t] = __builtin_amdgcn_mfma_f32_16x16x32_f16(a0, *(const f16x8*)(wd + q * 8), accv[t], 0, 0, 0);
        accv[t] = __builtin_amdgcn_mfma_f32_16x16x32_f16(a1, *(const f16x8*)(wd + 32 + q * 8), accv[t], 0, 0, 0);
        accv[t] = __builtin_amdgcn_mfma_f32_16x16x32_f16(a2, *(const f16x8*)(wd + 64 + q * 8), accv[t], 0, 0, 0);
        accv[t] = __builtin_amdgcn_mfma_f32_16x16x32_f16(a3, *(const f16x8*)(wd + 96 + q * 8), accv[t], 0, 0, 0);
    }
    int urow = ubase + q * 4;
#pragma unroll
    for (int t = 0; t < 4; ++t) {
        float bv = bias[t * 16 + m];
#pragma unroll
        for (int r = 0; r < 4; ++r) {
            int uu2 = urow + r;
            if (uu2 < nu) {
                u16 h = f2h(accv[t][r] + bv);
                sbuf[(size_t)uu2 * 64 + t * 16 + m] = h;
                if (wt) tbuf[(size_t)uu2 * 64 + t * 16 + m] = h;
            }
        }
    }
}

// ---- standalone final predictor ----
__global__ __launch_bounds__(256) void predl_kernel(const u16* __restrict__ xb,
        const int* __restrict__ l0, const int* __restrict__ l1,
        const float* __restrict__ pw, int ofA, int ofB,
        float* __restrict__ acc, int nl,
        const float* __restrict__ pb, float* __restrict__ out) {
    int li = blockIdx.x * 4 + (threadIdx.x >> 6);
    if (li >= nl) return;
    li = __builtin_amdgcn_readfirstlane(li);
    int lane = threadIdx.x & 63;
    int u = l0[li], v = l1[li];
    float s = pw[ofA + lane] * h2f(xb[(size_t)u * 64 + lane])
            + pw[ofB + lane] * h2f(xb[(size_t)v * 64 + lane]);
#pragma unroll
    for (int off = 32; off > 0; off >>= 1) s += __shfl_xor(s, off, 64);
    if (lane == 0) {
        float t = acc[li] + s + pb[0];
        t = t > 0.f ? t : 0.01f * t;
        out[li] = 1.f / (1.f + expf(-t));
    }
}

extern "C" void kernel_launch(void* const* d_in, const int* in_sizes, int n_in,
                              void* d_out, int out_size, void* d_ws, size_t ws_size,
                              hipStream_t stream) {
    const int*   se  = (const int*)d_in[0];   // [2,E] src then dst
    const int*   te  = (const int*)d_in[1];
    const int*   lk  = (const int*)d_in[2];   // [2,NLINK]
    const float* emb = (const float*)d_in[3]; // [N,64]
    const float* mw  = (const float*)d_in[4]; // [3,64,128]
    const float* mb  = (const float*)d_in[5]; // [3,64]
    const float* pw  = (const float*)d_in[6]; // [1,512]
    const float* pb  = (const float*)d_in[7]; // [1]
    float* out = (float*)d_out;

    const int E  = in_sizes[0] / 2;
    const int NL = in_sizes[2] / 2;
    const int N  = in_sizes[3] / 64;
    const int U  = 100000;
    const int NB = (N + NODESB - 1) >> BSHIFT;   // 782 coarse buckets

    char* p = (char*)d_ws;
    auto alloc = [&](size_t bytes) -> char* {
        char* r = p;
        p += (bytes + 255) & ~(size_t)255;
        return r;
    };
    const size_t bufb = (size_t)N * 128;                    // one node buffer, bytes
    const size_t colb = (size_t)NB * BCKCAP * 4;            // static-bucket col buffer
    const bool contig = (bufb % 256) == 0;                  // pair layout needs no pad
    auto rnd = [](size_t b) { return (b + 255) & ~(size_t)255; };
    size_t wide_total = 4 * rnd(bufb) + 2 * rnd(colb) + 4 * rnd((size_t)(N + 1) * 4)
                      + rnd((size_t)NL * 4) + rnd(2 * NBPAD * 4)
                      + rnd(3 * 64 * 128 * 2) + rnd((size_t)N);
    bool wide = contig && (wide_total <= ws_size);

    u32 *A, *B, *C, *Dd = nullptr;
    if (wide) {
        A  = (u32*)alloc(bufb);   // pair P1 = [A | B]   (s-chain | t-chain)
        B  = (u32*)alloc(bufb);
        C  = (u32*)alloc(bufb);   // pair P2 = [C | Dd]
        Dd = (u32*)alloc(bufb);
    } else {
        A  = (u32*)alloc(bufb);
        B  = (u32*)alloc(bufb);
        C  = (u32*)alloc(bufb);
    }
    u32* col_s = (u32*)alloc(colb);
    u32* col_t = (u32*)alloc(colb);
    int* rs_s  = (int*)alloc((size_t)(N + 1) * 4);
    int* rs_t  = (int*)alloc((size_t)(N + 1) * 4);
    int* dg_s  = (int*)alloc((size_t)(N + 1) * 4);
    int* dg_t  = (int*)alloc((size_t)(N + 1) * 4);
    float* acc = (float*)alloc((size_t)NL * 4);
    int* cur2  = (int*)alloc(2 * NBPAD * 4);
    u16* mwb   = (u16*)alloc(3 * 64 * 128 * 2);
    unsigned char* flags = (unsigned char*)alloc((size_t)N);

    hipMemsetAsync(cur2, 0, 2 * NBPAD * 4, stream);
    hipMemsetAsync(flags, 0, (size_t)N, stream);

    const int NBIN  = (E + BCHUNK - 1) / BCHUNK;     // 367
    const int NWPREP = 96;
    const int NCONV = (N * 64 + 1023) / 1024;        // 12500
    const int GA    = (N + 15) / 16;                 // 12500 agg blocks (16 nodes/block)
    const int GAU   = (U + 15) / 16;                 // 6250 (layer-3 t-agg: users only)
    const int GP    = (NL + 3) / 4;                  // 25000
    const int GM    = (U + 63) / 64;                 // 1563
    const int ECOL  = NB * BCKCAP;                   // 3,403,264 col entries
    const int NRB   = (ECOL + 1023) / 1024;          // remap blocks (4 entries/thread)

    // D1: MERGED bin both + W/emb conv + pred0/flags (independent, overlap)
    prep_all<<<2 * NBIN + NWPREP + NCONV + GP, 256, 0, stream>>>(
        se, se + E, te, te + E, E, cur2, col_s, col_t, NBIN,
        mw, mwb, emb, C, N * 64, NWPREP, NCONV,
        lk, lk + NL, pw, acc, NL, flags);
    // D2: sort both (reads per-bucket counts from cur2; writes rs+deg)
    sort2_kernel<<<2 * NB, 256, 0, stream>>>(col_s, col_t, cur2, cur2 + NBPAD,
                                             rs_s, rs_t, dg_s, dg_t, N, NB);

    if (wide) {
        // L1 merged: both lists gather C (full sharing, unmapped cols) -> A (s1), B (t1)
        aggp_kernel<<<2 * GA, 256, 0, stream>>>(
            C, rs_s, dg_s, col_s, A, GA, N, nullptr,
            C, rs_t, dg_t, col_t, B, GA, N, nullptr,
            (const u16*)nullptr, nullptr, nullptr, nullptr, 0, 0, nullptr, 0, 0);
        // mix1 (write A users only) + col_t remap (src<U ? src : src+N)
        mix_mfma<<<GM + NRB, 256, 0, stream>>>((u16*)A, (u16*)B, mwb + 0 * 8192, mb + 0 * 64,
                                               U, 0, col_t, ECOL, NRB, (u32)U, (u32)N, nullptr);
        // L2 merged + pred1(A): s: base A, col_s -> C ; t: base A (remapped col_t spans A|B) -> Dd
        aggp_kernel<<<GP + 2 * GA, 256, 0, stream>>>(
            A, rs_s, dg_s, col_s, C, GA, N, nullptr,
            A, rs_t, dg_t, col_t, Dd, GA, N, nullptr,
            (const u16*)A, lk, lk + NL, pw, 64, 320, acc, NL, GP);
        // mix2 (write C users only)
        mix_mfma<<<GM, 256, 0, stream>>>((u16*)C, (u16*)Dd, mwb + 1 * 8192, mb + 1 * 64,
                                         U, 0, nullptr, 0, 0, 0, 0, nullptr);
        // L3 merged + pred2(C): s: base C, col_s -> A (flagged nodes only) ;
        //                       t: base C (remapped col_t spans C|Dd) -> B (flagged users only)
        aggp_kernel<<<GP + GA + GAU, 256, 0, stream>>>(
            C, rs_s, dg_s, col_s, A, GA, N, flags,
            C, rs_t, dg_t, col_t, B, GAU, U, flags,
            (const u16*)C, lk, lk + NL, pw, 128, 384, acc, NL, GP);
        // mix3 (write A users only; waves with no flagged users skip)
        mix_mfma<<<GM, 256, 0, stream>>>((u16*)A, (u16*)B, mwb + 2 * 8192, mb + 2 * 64,
                                         U, 0, nullptr, 0, 0, 0, 0, flags);
        // final predictor on A (s-chain L3 mixed)
        predl_kernel<<<GP, 256, 0, stream>>>((const u16*)A, lk, lk + NL, pw, 192, 448, acc, NL, pb, out);
    } else {
        // ---- fallback: 3-buffer sequential schedule, unmapped cols ----
        aggp_kernel<<<2 * GA, 256, 0, stream>>>(
            C, rs_s, dg_s, col_s, A, GA, N, nullptr,
            C, rs_t, dg_t, col_t, B, GA, N, nullptr,
            (const u16*)nullptr, nullptr, nullptr, nullptr, 0, 0, nullptr, 0, 0);
        mix_mfma<<<GM, 256, 0, stream>>>((u16*)A, (u16*)B, mwb + 0 * 8192, mb + 0 * 64,
                                         U, 1, nullptr, 0, 0, 0, 0, nullptr);
        aggp_kernel<<<GP + GA, 256, 0, stream>>>(
            A, rs_s, dg_s, col_s, C, GA, N, nullptr,
            nullptr, nullptr, nullptr, nullptr, nullptr, 0, 0, nullptr,
            (const u16*)A, lk, lk + NL, pw, 64, 320, acc, NL, GP);
        aggp_kernel<<<GA, 256, 0, stream>>>(
            B, rs_t, dg_t, col_t, A, GA, N, nullptr,
            nullptr, nullptr, nullptr, nullptr, nullptr, 0, 0, nullptr,
            (const u16*)nullptr, nullptr, nullptr, nullptr, 0, 0, nullptr, 0, 0);
        mix_mfma<<<GM, 256, 0, stream>>>((u16*)C, (u16*)A, mwb + 1 * 8192, mb + 1 * 64,
                                         U, 1, nullptr, 0, 0, 0, 0, nullptr);
        aggp_kernel<<<GP + GA, 256, 0, stream>>>(
            C, rs_s, dg_s, col_s, B, GA, N, nullptr,
            nullptr, nullptr, nullptr, nullptr, nullptr, 0, 0, nullptr,
            (const u16*)C, lk, lk + NL, pw, 128, 384, acc, NL, GP);
        aggp_kernel<<<GAU, 256, 0, stream>>>(
            A, rs_t, dg_t, col_t, C, GAU, U, nullptr,
            nullptr, nullptr, nullptr, nullptr, nullptr, 0, 0, nullptr,
            (const u16*)nullptr, nullptr, nullptr, nullptr, 0, 0, nullptr, 0, 0);
        mix_mfma<<<GM, 256, 0, stream>>>((u16*)B, (u16*)C, mwb + 2 * 8192, mb + 2 * 64,
                                         U, 1, nullptr, 0, 0, 0, 0, nullptr);
        predl_kernel<<<GP, 256, 0, stream>>>((const u16*)B, lk, lk + NL, pw, 192, 448, acc, NL, pb, out);
    }
}

// Round 13
// 658.743 us; speedup vs baseline: 1.0217x; 1.0217x over previous
//
#include <hip/hip_runtime.h>
#include <hip/hip_bf16.h>
#include <math.h>

// N=200000 nodes, U=100000 users, D=64, L=3, E=3,000,000 per edge list, NLINK=100000.
// Node buffers FP16; aggregation accumulates via v_dot2_f32_f16.
// Agg: r5 floor config (TRIPLE-confirmed delivery-ceiling) — DO NOT TOUCH.
// Prep: STATIC bucket bases; bin3 SEPARATE (45KB LDS, r12 lesson: merging light
// blocks into a fat-LDS kernel tanks their occupancy to 3 blocks/CU). W/emb-conv
// + pred0 are merged into SORT2 instead (18KB LDS -> 8 blocks/CU), hiding their
// ~20us under the sort. CSR is (rs, deg) pairs.
// L3: BOTH lists flag-skipped; mix3 waves with no flagged users skip.
// Wide mode: node buffers as contiguous PAIRS (A|B, C|Dd); t-chain gathers use
// remapped col_t (src<U ? src : src+N) sharing user rows with the s-chain.

typedef unsigned short u16;
typedef unsigned int   u32;
typedef __attribute__((ext_vector_type(2))) _Float16 h16x2;
typedef __attribute__((ext_vector_type(8))) _Float16 f16x8;
typedef __attribute__((ext_vector_type(4))) float f32x4;

#define BSHIFT 8                 // 256 nodes per coarse bucket
#define NODESB 256               // nodes per bucket
#define NBPAD  1024              // padded bucket-cursor array (782 used)
#define BCKCAP 4352              // static bucket capacity (mean 3840, +8 sigma)
#define BCAP   4096              // LDS staging per sort bucket
#define OVF    8                 // +2048 entries of per-thread register headroom
#define BCHUNK 8192              // edges per bin block (LDS presort)

__device__ __forceinline__ u16 f2h(float f) {
    _Float16 h = (_Float16)f;
    return __builtin_bit_cast(u16, h);
}
__device__ __forceinline__ float h2f(u16 v) {
    _Float16 h = __builtin_bit_cast(_Float16, v);
    return (float)h;
}
__device__ __forceinline__ u32 packh2(float a, float b) {
    auto r = __builtin_amdgcn_cvt_pkrtz(a, b);   // v_cvt_pkrtz_f16_f32 (__fp16 x2)
    return __builtin_bit_cast(u32, r);
}
__device__ __forceinline__ float hlo(u32 p) {
    h16x2 h = __builtin_bit_cast(h16x2, p);
    return (float)h.x;
}
__device__ __forceinline__ float hhi(u32 p) {
    h16x2 h = __builtin_bit_cast(h16x2, p);
    return (float)h.y;
}
__device__ __forceinline__ int imin(int a, int b) { return a < b ? a : b; }

#if defined(__has_builtin)
#if __has_builtin(__builtin_amdgcn_fdot2)
#define HAVE_FDOT2 1
#endif
#endif

// ---- D1: binning via block-local LDS presort; STATIC bucket bases (r11 exact) ----
__global__ __launch_bounds__(256) void bin3_kernel(const int* __restrict__ ssrc,
        const int* __restrict__ sdst, const int* __restrict__ tsrc, const int* __restrict__ tdst,
        int e, int* __restrict__ cur2, u32* __restrict__ bin_s, u32* __restrict__ bin_t,
        int nbin) {
    __shared__ u32 stage[BCHUNK];       // 32KB bucket-sorted staging
    __shared__ int lcnt[NBPAD];
    __shared__ int lofs[NBPAD];
    __shared__ int lbase[NBPAD];
    __shared__ int part[256];
    int bid = blockIdx.x, tid = threadIdx.x;
    const int* src; const int* dst; int* cursor; u32* bin; int cb;
    if (bid < nbin) { src = ssrc; dst = sdst; cursor = cur2; bin = bin_s; cb = bid; }
    else { src = tsrc; dst = tdst; cursor = cur2 + NBPAD; bin = bin_t; cb = bid - nbin; }
    for (int i = tid; i < NBPAD; i += 256) lcnt[i] = 0;
    __syncthreads();
    int base = cb * BCHUNK, end = imin(base + BCHUNK, e);
    // A: histogram chunk by bucket
    for (int i = base + tid; i < end; i += 256)
        atomicAdd(&lcnt[(u32)dst[i] >> BSHIFT], 1);
    __syncthreads();
    // B: block scan -> lofs; bulk reservation (static base + cursor) -> lbase
    {
        int i0 = tid * 4;
        int c[4]; int s = 0;
#pragma unroll
        for (int j = 0; j < 4; ++j) { c[j] = lcnt[i0 + j]; s += c[j]; }
        part[tid] = s;
        __syncthreads();
        for (int off = 1; off < 256; off <<= 1) {
            int t = (tid >= off) ? part[tid - off] : 0;
            __syncthreads();
            part[tid] += t;
            __syncthreads();
        }
        int excl = part[tid] - s;
#pragma unroll
        for (int j = 0; j < 4; ++j) {
            int idx = i0 + j;
            lofs[idx]  = excl;
            lbase[idx] = c[j] ? (idx * BCKCAP + atomicAdd(&cursor[idx], c[j])) : 0;
            lcnt[idx]  = excl;          // scatter cursor starts at bucket start
            excl += c[j];
        }
    }
    __syncthreads();
    // C: scatter entries into LDS staging, bucket-sorted
    for (int i = base + tid; i < end; i += 256) {
        int d = dst[i];
        int b = (u32)d >> BSHIFT;
        int p = atomicAdd(&lcnt[b], 1);
        stage[p] = (u32)src[i] | ((u32)(d & (NODESB - 1)) << 18);   // src < 2^18
    }
    __syncthreads();
    // D: flush segments, 4 lanes per bucket -> contiguous burst writes
    for (int bb = tid >> 2; bb < NBPAD; bb += 64) {
        int lo = lofs[bb];
        int cnt = lcnt[bb] - lo;
        int gb = lbase[bb];
        for (int j = tid & 3; j < cnt; j += 4)
            bin[gb + j] = stage[lo + j];
    }
}

// ---- D2: MERGED sort2 (18KB LDS) + W/emb->f16 conv + pred0/flags ----
// Block roles: [0, 2*nb) sort ; [.., +nwprep+nconv) conv ; rest pred0.
// Light blocks ride at sort2's 8-blocks/CU occupancy (r12 lesson applied).
__global__ __launch_bounds__(256) void sortcp_kernel(u32* __restrict__ bin_s, u32* __restrict__ bin_t,
        const int* __restrict__ cnt_s, const int* __restrict__ cnt_t,
        int* __restrict__ rs_s, int* __restrict__ rs_t,
        int* __restrict__ dg_s, int* __restrict__ dg_t, int n, int nb,
        const float* __restrict__ mw, u16* __restrict__ mwb,
        const float* __restrict__ emb, u32* __restrict__ embb, int nelem, int nwprep, int nconv,
        const int* __restrict__ l0, const int* __restrict__ l1,
        const float* __restrict__ pw, float* __restrict__ acc, int nl,
        unsigned char* __restrict__ flag) {
    __shared__ u32 ent[BCAP];           // 16KB (sort branch only touches it)
    __shared__ int cnt[NODESB];
    __shared__ int part[256];
    int bid = blockIdx.x, tid = threadIdx.x;
    if (bid < 2 * nb) {
        u32* bin; const int* bcnt; int* rowstart; int* degarr; int b;
        if (bid < nb) { bin = bin_s; bcnt = cnt_s; rowstart = rs_s; degarr = dg_s; b = bid; }
        else { bin = bin_t; bcnt = cnt_t; rowstart = rs_t; degarr = dg_t; b = bid - nb; }
        int beg = b * BCKCAP;
        int sz = bcnt[b];
        cnt[tid] = 0;
        __syncthreads();
        u32 ovf[OVF];
        for (int i = tid; i < sz; i += 256) {
            u32 v = bin[beg + i];
            if (i < BCAP) ent[i] = v;
            else { int k = (i - BCAP) >> 8; if (k < OVF) ovf[k] = v; }
            atomicAdd(&cnt[v >> 18], 1);
        }
        __syncthreads();
        int c = cnt[tid];
        part[tid] = c;
        __syncthreads();
        for (int off = 1; off < 256; off <<= 1) {
            int t = (tid >= off) ? part[tid - off] : 0;
            __syncthreads();
            part[tid] += t;
            __syncthreads();
        }
        int excl = part[tid] - c;
        int node = (b << BSHIFT) + tid;
        if (node < n) { rowstart[node] = beg + excl; degarr[node] = c; }
        cnt[tid] = excl;             // running cursor for scatter phase
        __syncthreads();
        for (int i = tid; i < sz; i += 256) {
            u32 v;
            if (i < BCAP) v = ent[i];
            else { int k = (i - BCAP) >> 8; v = (k < OVF) ? ovf[k] : bin[beg + i]; }
            int pos = atomicAdd(&cnt[v >> 18], 1);
            bin[beg + pos] = v & 0x3FFFFu;
        }
        return;
    }
    bid -= 2 * nb;
    if (bid < nwprep + nconv) {
        if (bid < nwprep) {
            int idx = bid * 256 + tid;
            if (idx < 3 * 64 * 128) mwb[idx] = f2h(mw[idx]);
        } else {
            int idx = (bid - nwprep) * 1024 + tid * 4;   // 4 floats / thread
            if (idx < nelem) {
                float4 v = *(const float4*)(emb + idx);
                uint2 r;
                r.x = packh2(v.x, v.y);
                r.y = packh2(v.z, v.w);
                *(uint2*)(embb + (idx >> 1)) = r;
            }
        }
        return;
    }
    bid -= nwprep + nconv;
    int li = bid * 4 + (tid >> 6);
    if (li >= nl) return;
    li = __builtin_amdgcn_readfirstlane(li);
    int lane = tid & 63;
    int u = l0[li], v = l1[li];
    if (lane == 0) { flag[u] = 1; flag[v] = 1; }   // L3 liveness
    float s = pw[lane] * emb[(size_t)u * 64 + lane] + pw[256 + lane] * emb[(size_t)v * 64 + lane];
#pragma unroll
    for (int off = 32; off > 0; off >>= 1) s += __shfl_xor(s, off, 64);
    if (lane == 0) acc[li] = s;
}

// ---- mean aggregation (f16 in/out, fdot2) + fused predictor blocks ----
// r5 floor config: 16 lanes/node (8 feat x 2 groups), 4 nodes/wave, 8-slot
// blocks with FOUR row loads in flight; clamped slots overcount row[col[dgm1]]
// (last block only), removed by exact conditional subtracts after the loop.
__global__ __launch_bounds__(256) void aggp_kernel(
        const u32* __restrict__ x0, const int* __restrict__ rsA, const int* __restrict__ dgA,
        const u32* __restrict__ colA, u32* __restrict__ outA, int nblkA, int nA,
        const unsigned char* __restrict__ skipA,
        const u32* __restrict__ x1, const int* __restrict__ rsB, const int* __restrict__ dgB,
        const u32* __restrict__ colB, u32* __restrict__ outB, int nblkB, int nB,
        const unsigned char* __restrict__ skipB,
        const u16* __restrict__ px, const int* __restrict__ l0, const int* __restrict__ l1,
        const float* __restrict__ pw, int ofA, int ofB, float* __restrict__ acc, int nl,
        int npred) {
    int bid = blockIdx.x;
    int lane = threadIdx.x & 63;
    if (bid < npred) {
        int li = bid * 4 + (threadIdx.x >> 6);
        if (li >= nl) return;
        li = __builtin_amdgcn_readfirstlane(li);
        int u = l0[li], v = l1[li];
        float s = pw[ofA + lane] * h2f(px[(size_t)u * 64 + lane])
                + pw[ofB + lane] * h2f(px[(size_t)v * 64 + lane]);
#pragma unroll
        for (int off = 32; off > 0; off >>= 1) s += __shfl_xor(s, off, 64);
        if (lane == 0) acc[li] += s;
        return;
    }
    bid -= npred;
    const u32* xin; const int* rs; const int* dg; const u32* col; u32* out; int nlim;
    const unsigned char* skip;
    if (bid < nblkA) { xin = x0; rs = rsA; dg = dgA; col = colA; out = outA; nlim = nA; skip = skipA; }
    else { bid -= nblkA; xin = x1; rs = rsB; dg = dgB; col = colB; out = outB; nlim = nB; skip = skipB; }
    int node = bid * 16 + (threadIdx.x >> 4);   // one node per 16-lane quarter-wave
    if (node >= nlim) return;
    if (skip && !skip[node]) return;            // output never read downstream
    int fl = lane & 7;            // feature octet: features 8fl .. 8fl+7
    int g  = (lane >> 3) & 1;     // edge group 0..1 within the 16-lane group
    int beg = rs[node];
    int dgv = dg[node];
    int dgm1 = dgv - 1;
    float a0 = 0.f, a1 = 0.f, a2 = 0.f, a3 = 0.f, a4 = 0.f, a5 = 0.f, a6 = 0.f, a7 = 0.f;
    uint4 p0 = make_uint4(0, 0, 0, 0), p1 = make_uint4(0, 0, 0, 0);
    uint4 p2 = make_uint4(0, 0, 0, 0), p3 = make_uint4(0, 0, 0, 0);
    const uint4* xb = (const uint4*)xin;
    const h16x2 SLO = {(_Float16)1.f, (_Float16)0.f};
    const h16x2 SHI = {(_Float16)0.f, (_Float16)1.f};
#ifdef HAVE_FDOT2
#define ACC8(P) { \
    h16x2 w0 = __builtin_bit_cast(h16x2, (P).x), w1 = __builtin_bit_cast(h16x2, (P).y); \
    h16x2 w2 = __builtin_bit_cast(h16x2, (P).z), w3 = __builtin_bit_cast(h16x2, (P).w); \
    a0 = __builtin_amdgcn_fdot2(w0, SLO, a0, false); a1 = __builtin_amdgcn_fdot2(w0, SHI, a1, false); \
    a2 = __builtin_amdgcn_fdot2(w1, SLO, a2, false); a3 = __builtin_amdgcn_fdot2(w1, SHI, a3, false); \
    a4 = __builtin_amdgcn_fdot2(w2, SLO, a4, false); a5 = __builtin_amdgcn_fdot2(w2, SHI, a5, false); \
    a6 = __builtin_amdgcn_fdot2(w3, SLO, a6, false); a7 = __builtin_amdgcn_fdot2(w3, SHI, a7, false); }
#else
#define ACC8(P) { \
    a0 += hlo((P).x); a1 += hhi((P).x); a2 += hlo((P).y); a3 += hhi((P).y); \
    a4 += hlo((P).z); a5 += hhi((P).z); a6 += hlo((P).w); a7 += hhi((P).w); }
#endif
#define SUB8(P) { \
    a0 -= hlo((P).x); a1 -= hhi((P).x); a2 -= hlo((P).y); a3 -= hhi((P).y); \
    a4 -= hlo((P).z); a5 -= hhi((P).z); a6 -= hlo((P).w); a7 -= hhi((P).w); }
    if (dgv > 0) {
        int s0 = col[beg + imin(g, dgm1)];
        int s1 = col[beg + imin(g + 2, dgm1)];
        int s2 = col[beg + imin(g + 4, dgm1)];
        int s3 = col[beg + imin(g + 6, dgm1)];
        for (int jb = 0; jb < dgv; jb += 8) {
            p0 = xb[(size_t)s0 * 8 + fl];
            p1 = xb[(size_t)s1 * 8 + fl];
            p2 = xb[(size_t)s2 * 8 + fl];
            p3 = xb[(size_t)s3 * 8 + fl];
            int nj = jb + 8 + g;
            s0 = col[beg + imin(nj, dgm1)];       // prefetch next block's cols
            s1 = col[beg + imin(nj + 2, dgm1)];
            s2 = col[beg + imin(nj + 4, dgm1)];
            s3 = col[beg + imin(nj + 6, dgm1)];
            ACC8(p0); ACC8(p1); ACC8(p2); ACC8(p3);
        }
        int jbl = (dgm1 >> 3) << 3;               // last iteration's block base
        if (jbl + g > dgm1)     SUB8(p0);
        if (jbl + 2 + g > dgm1) SUB8(p1);
        if (jbl + 4 + g > dgm1) SUB8(p2);
        if (jbl + 6 + g > dgm1) SUB8(p3);
    }
    // reduce over the 2 edge groups (lanes x ^ x+8 within each 16-lane node)
    a0 += __shfl_xor(a0, 8, 64); a1 += __shfl_xor(a1, 8, 64);
    a2 += __shfl_xor(a2, 8, 64); a3 += __shfl_xor(a3, 8, 64);
    a4 += __shfl_xor(a4, 8, 64); a5 += __shfl_xor(a5, 8, 64);
    a6 += __shfl_xor(a6, 8, 64); a7 += __shfl_xor(a7, 8, 64);
    if (g == 0) {
        float inv = __builtin_amdgcn_rcpf((float)(dgv > 1 ? dgv : 1));
        uint4 r;
        r.x = packh2(a0 * inv, a1 * inv);
        r.y = packh2(a2 * inv, a3 * inv);
        r.z = packh2(a4 * inv, a5 * inv);
        r.w = packh2(a6 * inv, a7 * inv);
        ((uint4*)out)[(size_t)node * 8 + fl] = r;
    }
#undef ACC8
#undef SUB8
}

// ---- user mix via MFMA (f16) + optional fused col_t remap blocks ----
// uflag != nullptr (mix3): waves whose 16 users are all unflagged skip.
__global__ __launch_bounds__(256) void mix_mfma(u16* __restrict__ sbuf, u16* __restrict__ tbuf,
        const u16* __restrict__ wb /*[64][128] f16*/, const float* __restrict__ bias, int nu,
        int wt, u32* __restrict__ colt, int ecnt, int nrb, u32 uu, u32 nn,
        const unsigned char* __restrict__ uflag) {
    int bid = blockIdx.x;
    if (bid < nrb) {
        int idx = (bid * 256 + (int)threadIdx.x) * 4;
        if (idx + 3 < ecnt) {
            uint4 v = *(uint4*)(colt + idx);
            v.x = v.x >= uu ? v.x + nn : v.x;
            v.y = v.y >= uu ? v.y + nn : v.y;
            v.z = v.z >= uu ? v.z + nn : v.z;
            v.w = v.w >= uu ? v.w + nn : v.w;
            *(uint4*)(colt + idx) = v;
        } else {
            for (int k = idx; k < ecnt; ++k) { u32 e = colt[k]; colt[k] = e >= uu ? e + nn : e; }
        }
        return;
    }
    bid -= nrb;
    int lane = threadIdx.x & 63;
    int wv = threadIdx.x >> 6;
    int m = lane & 15, q = lane >> 4;
    int ubase = bid * 64 + wv * 16;
    int ul = ubase + m;
    int usafe = ul < nu ? ul : nu - 1;
    if (uflag) {
        unsigned long long any = __ballot(uflag[usafe] != 0);
        if (any == 0ull) return;            // whole wave's 16 users dead
    }
    const f16x8* srow = (const f16x8*)(sbuf + (size_t)usafe * 64);
    const f16x8* trow = (const f16x8*)(tbuf + (size_t)usafe * 64);
    f16x8 a0 = srow[q];
    f16x8 a1 = srow[4 + q];
    f16x8 a2 = trow[q];
    f16x8 a3 = trow[4 + q];
    f32x4 accv[4];
#pragma unroll
    for (int t = 0; t < 4; ++t) { accv[t].x = accv[t].y = accv[t].z = accv[t].w = 0.f; }
#pragma unroll
    for (int t = 0; t < 4; ++t) {
        const u16* wd = wb + (size_t)(t * 16 + m) * 128;
        accv[t] = __builtin_amdgcn_mfma_f32_16x16x32_f16(a0, *(const f16x8*)(wd + q * 8), accv[t], 0, 0, 0);
        accv[t] = __builtin_amdgcn_mfma_f32_16x16x32_f16(a1, *(const f16x8*)(wd + 32 + q * 8), accv[t], 0, 0, 0);
        accv[t] = __builtin_amdgcn_mfma_f32_16x16x32_f16(a2, *(const f16x8*)(wd + 64 + q * 8), accv[t], 0, 0, 0);
        accv[t] = __builtin_amdgcn_mfma_f32_16x16x32_f16(a3, *(const f16x8*)(wd + 96 + q * 8), accv[t], 0, 0, 0);
    }
    int urow = ubase + q * 4;
#pragma unroll
    for (int t = 0; t < 4; ++t) {
        float bv = bias[t * 16 + m];
#pragma unroll
        for (int r = 0; r < 4; ++r) {
            int uu2 = urow + r;
            if (uu2 < nu) {
                u16 h = f2h(accv[t][r] + bv);
                sbuf[(size_t)uu2 * 64 + t * 16 + m] = h;
                if (wt) tbuf[(size_t)uu2 * 64 + t * 16 + m] = h;
            }
        }
    }
}

// ---- standalone final predictor ----
__global__ __launch_bounds__(256) void predl_kernel(const u16* __restrict__ xb,
        const int* __restrict__ l0, const int* __restrict__ l1,
        const float* __restrict__ pw, int ofA, int ofB,
        float* __restrict__ acc, int nl,
        const float* __restrict__ pb, float* __restrict__ out) {
    int li = blockIdx.x * 4 + (threadIdx.x >> 6);
    if (li >= nl) return;
    li = __builtin_amdgcn_readfirstlane(li);
    int lane = threadIdx.x & 63;
    int u = l0[li], v = l1[li];
    float s = pw[ofA + lane] * h2f(xb[(size_t)u * 64 + lane])
            + pw[ofB + lane] * h2f(xb[(size_t)v * 64 + lane]);
#pragma unroll
    for (int off = 32; off > 0; off >>= 1) s += __shfl_xor(s, off, 64);
    if (lane == 0) {
        float t = acc[li] + s + pb[0];
        t = t > 0.f ? t : 0.01f * t;
        out[li] = 1.f / (1.f + expf(-t));
    }
}

extern "C" void kernel_launch(void* const* d_in, const int* in_sizes, int n_in,
                              void* d_out, int out_size, void* d_ws, size_t ws_size,
                              hipStream_t stream) {
    const int*   se  = (const int*)d_in[0];   // [2,E] src then dst
    const int*   te  = (const int*)d_in[1];
    const int*   lk  = (const int*)d_in[2];   // [2,NLINK]
    const float* emb = (const float*)d_in[3]; // [N,64]
    const float* mw  = (const float*)d_in[4]; // [3,64,128]
    const float* mb  = (const float*)d_in[5]; // [3,64]
    const float* pw  = (const float*)d_in[6]; // [1,512]
    const float* pb  = (const float*)d_in[7]; // [1]
    float* out = (float*)d_out;

    const int E  = in_sizes[0] / 2;
    const int NL = in_sizes[2] / 2;
    const int N  = in_sizes[3] / 64;
    const int U  = 100000;
    const int NB = (N + NODESB - 1) >> BSHIFT;   // 782 coarse buckets

    char* p = (char*)d_ws;
    auto alloc = [&](size_t bytes) -> char* {
        char* r = p;
        p += (bytes + 255) & ~(size_t)255;
        return r;
    };
    const size_t bufb = (size_t)N * 128;                    // one node buffer, bytes
    const size_t colb = (size_t)NB * BCKCAP * 4;            // static-bucket col buffer
    const bool contig = (bufb % 256) == 0;                  // pair layout needs no pad
    auto rnd = [](size_t b) { return (b + 255) & ~(size_t)255; };
    size_t wide_total = 4 * rnd(bufb) + 2 * rnd(colb) + 4 * rnd((size_t)(N + 1) * 4)
                      + rnd((size_t)NL * 4) + rnd(2 * NBPAD * 4)
                      + rnd(3 * 64 * 128 * 2) + rnd((size_t)N);
    bool wide = contig && (wide_total <= ws_size);

    u32 *A, *B, *C, *Dd = nullptr;
    if (wide) {
        A  = (u32*)alloc(bufb);   // pair P1 = [A | B]   (s-chain | t-chain)
        B  = (u32*)alloc(bufb);
        C  = (u32*)alloc(bufb);   // pair P2 = [C | Dd]
        Dd = (u32*)alloc(bufb);
    } else {
        A  = (u32*)alloc(bufb);
        B  = (u32*)alloc(bufb);
        C  = (u32*)alloc(bufb);
    }
    u32* col_s = (u32*)alloc(colb);
    u32* col_t = (u32*)alloc(colb);
    int* rs_s  = (int*)alloc((size_t)(N + 1) * 4);
    int* rs_t  = (int*)alloc((size_t)(N + 1) * 4);
    int* dg_s  = (int*)alloc((size_t)(N + 1) * 4);
    int* dg_t  = (int*)alloc((size_t)(N + 1) * 4);
    float* acc = (float*)alloc((size_t)NL * 4);
    int* cur2  = (int*)alloc(2 * NBPAD * 4);
    u16* mwb   = (u16*)alloc(3 * 64 * 128 * 2);
    unsigned char* flags = (unsigned char*)alloc((size_t)N);

    hipMemsetAsync(cur2, 0, 2 * NBPAD * 4, stream);
    hipMemsetAsync(flags, 0, (size_t)N, stream);

    const int NBIN  = (E + BCHUNK - 1) / BCHUNK;     // 367
    const int NWPREP = 96;
    const int NCONV = (N * 64 + 1023) / 1024;        // 12500
    const int GA    = (N + 15) / 16;                 // 12500 agg blocks (16 nodes/block)
    const int GAU   = (U + 15) / 16;                 // 6250 (layer-3 t-agg: users only)
    const int GP    = (NL + 3) / 4;                  // 25000
    const int GM    = (U + 63) / 64;                 // 1563
    const int ECOL  = NB * BCKCAP;                   // 3,403,264 col entries
    const int NRB   = (ECOL + 1023) / 1024;          // remap blocks (4 entries/thread)

    // D1: bin both (45KB LDS, own kernel — r12 lesson)
    bin3_kernel<<<2 * NBIN, 256, 0, stream>>>(se, se + E, te, te + E, E, cur2, col_s, col_t, NBIN);
    // D2: MERGED sort2 + W/emb conv + pred0/flags (18KB LDS, 8 blocks/CU)
    sortcp_kernel<<<2 * NB + NWPREP + NCONV + GP, 256, 0, stream>>>(
        col_s, col_t, cur2, cur2 + NBPAD, rs_s, rs_t, dg_s, dg_t, N, NB,
        mw, mwb, emb, C, N * 64, NWPREP, NCONV,
        lk, lk + NL, pw, acc, NL, flags);

    if (wide) {
        // L1 merged: both lists gather C (full sharing, unmapped cols) -> A (s1), B (t1)
        aggp_kernel<<<2 * GA, 256, 0, stream>>>(
            C, rs_s, dg_s, col_s, A, GA, N, nullptr,
            C, rs_t, dg_t, col_t, B, GA, N, nullptr,
            (const u16*)nullptr, nullptr, nullptr, nullptr, 0, 0, nullptr, 0, 0);
        // mix1 (write A users only) + col_t remap (src<U ? src : src+N)
        mix_mfma<<<GM + NRB, 256, 0, stream>>>((u16*)A, (u16*)B, mwb + 0 * 8192, mb + 0 * 64,
                                               U, 0, col_t, ECOL, NRB, (u32)U, (u32)N, nullptr);
        // L2 merged + pred1(A): s: base A, col_s -> C ; t: base A (remapped col_t spans A|B) -> Dd
        aggp_kernel<<<GP + 2 * GA, 256, 0, stream>>>(
            A, rs_s, dg_s, col_s, C, GA, N, nullptr,
            A, rs_t, dg_t, col_t, Dd, GA, N, nullptr,
            (const u16*)A, lk, lk + NL, pw, 64, 320, acc, NL, GP);
        // mix2 (write C users only)
        mix_mfma<<<GM, 256, 0, stream>>>((u16*)C, (u16*)Dd, mwb + 1 * 8192, mb + 1 * 64,
                                         U, 0, nullptr, 0, 0, 0, 0, nullptr);
        // L3 merged + pred2(C): s: base C, col_s -> A (flagged nodes only) ;
        //                       t: base C (remapped col_t spans C|Dd) -> B (flagged users only)
        aggp_kernel<<<GP + GA + GAU, 256, 0, stream>>>(
            C, rs_s, dg_s, col_s, A, GA, N, flags,
            C, rs_t, dg_t, col_t, B, GAU, U, flags,
            (const u16*)C, lk, lk + NL, pw, 128, 384, acc, NL, GP);
        // mix3 (write A users only; waves with no flagged users skip)
        mix_mfma<<<GM, 256, 0, stream>>>((u16*)A, (u16*)B, mwb + 2 * 8192, mb + 2 * 64,
                                         U, 0, nullptr, 0, 0, 0, 0, flags);
        // final predictor on A (s-chain L3 mixed)
        predl_kernel<<<GP, 256, 0, stream>>>((const u16*)A, lk, lk + NL, pw, 192, 448, acc, NL, pb, out);
    } else {
        // ---- fallback: 3-buffer sequential schedule, unmapped cols ----
        aggp_kernel<<<2 * GA, 256, 0, stream>>>(
            C, rs_s, dg_s, col_s, A, GA, N, nullptr,
            C, rs_t, dg_t, col_t, B, GA, N, nullptr,
            (const u16*)nullptr, nullptr, nullptr, nullptr, 0, 0, nullptr, 0, 0);
        mix_mfma<<<GM, 256, 0, stream>>>((u16*)A, (u16*)B, mwb + 0 * 8192, mb + 0 * 64,
                                         U, 1, nullptr, 0, 0, 0, 0, nullptr);
        aggp_kernel<<<GP + GA, 256, 0, stream>>>(
            A, rs_s, dg_s, col_s, C, GA, N, nullptr,
            nullptr, nullptr, nullptr, nullptr, nullptr, 0, 0, nullptr,
            (const u16*)A, lk, lk + NL, pw, 64, 320, acc, NL, GP);
        aggp_kernel<<<GA, 256, 0, stream>>>(
            B, rs_t, dg_t, col_t, A, GA, N, nullptr,
            nullptr, nullptr, nullptr, nullptr, nullptr, 0, 0, nullptr,
            (const u16*)nullptr, nullptr, nullptr, nullptr, 0, 0, nullptr, 0, 0);
        mix_mfma<<<GM, 256, 0, stream>>>((u16*)C, (u16*)A, mwb + 1 * 8192, mb + 1 * 64,
                                         U, 1, nullptr, 0, 0, 0, 0, nullptr);
        aggp_kernel<<<GP + GA, 256, 0, stream>>>(
            C, rs_s, dg_s, col_s, B, GA, N, nullptr,
            nullptr, nullptr, nullptr, nullptr, nullptr, 0, 0, nullptr,
            (const u16*)C, lk, lk + NL, pw, 128, 384, acc, NL, GP);
        aggp_kernel<<<GAU, 256, 0, stream>>>(
            A, rs_t, dg_t, col_t, C, GAU, U, nullptr,
            nullptr, nullptr, nullptr, nullptr, nullptr, 0, 0, nullptr,
            (const u16*)nullptr, nullptr, nullptr, nullptr, 0, 0, nullptr, 0, 0);
        mix_mfma<<<GM, 256, 0, stream>>>((u16*)B, (u16*)C, mwb + 2 * 8192, mb + 2 * 64,
                                         U, 1, nullptr, 0, 0, 0, 0, nullptr);
        predl_kernel<<<GP, 256, 0, stream>>>((const u16*)B, lk, lk + NL, pw, 192, 448, acc, NL, pb, out);
    }
}